// Round 5
// baseline (282.420 us; speedup 1.0000x reference)
//
#include <hip/hip_runtime.h>

namespace {
constexpr int S_LEN = 512;
constexpr int BATCH = 1024;
constexpr int TAG = 64;
constexpr int START_IDX = 0;
constexpr int END_IDX = 1;
constexpr float NEG_INF = -10000.0f;
constexpr int CHUNK = 64;              // steps per LDS feat chunk (16 KB)
constexpr float LN2F = 0.69314718055994530942f;

typedef float v2f __attribute__((ext_vector_type(2)));
typedef float v4f __attribute__((ext_vector_type(4)));

typedef const __attribute__((address_space(1))) void* gas_ptr;
typedef __attribute__((address_space(3))) void* las_ptr;

__device__ inline void gld_lds16(const float* g, float* l) {
  // LDS dest = wave-uniform base + lane*16 (hardware); global src is per-lane.
  __builtin_amdgcn_global_load_lds((gas_ptr)(const void*)g, (las_ptr)(void*)l, 16, 0, 0);
}
}

// One wave (64 lanes) per batch; lane = destination tag j.
// Linear-domain recurrence: p_j = exp(alpha_j - etot*ln2).
//   t_j = sum_i E[j,i] * p_i   via ds_write + 16 broadcast ds_read_b128 + 32 pk_fma
//   p_j' = t_j * cg_j          cg = exp(feat) (batched off-chain per 4 steps)
// Renormalization (exact power-of-2 from lane 2's exponent bits) happens once per
// 4 steps, and its readlane/SALU work is scheduled INSIDE the DS round-trip gap.
// p_lds is parity double-buffered so no WAR fence is needed between steps.
// Feats are staged 64 steps ahead into double-buffered LDS via global_load_lds;
// mask is collapsed to L = sum(mask) once at entry (mask monotone in s).
__global__ __launch_bounds__(64, 1) void crf_fwd_kernel(
    const float* __restrict__ feats,   // [S, B, T]
    const float* __restrict__ mask,    // [S, B]
    const float* __restrict__ trans,   // [T, T]
    float* __restrict__ out) {         // [B]
  const int b = blockIdx.x;
  const int lane = threadIdx.x;  // tag j

  __shared__ __align__(16) float fchunk[2][CHUNK * TAG];  // 2 x 16 KB
  __shared__ __align__(16) float p_lds[2][TAG];           // parity double-buffer

  // ---- effective length L = sum_s mask[s,b] (mask monotone non-increasing) ----
  int L;
  {
    float sum = 0.0f;
#pragma unroll
    for (int k = 0; k < S_LEN / 64; ++k) sum += mask[(size_t)(lane + 64 * k) * BATCH + b];
#pragma unroll
    for (int off = 32; off >= 1; off >>= 1) sum += __shfl_xor(sum, off, 64);
    L = (int)(sum + 0.5f);
  }

  // ---- one-time: E row j into registers (exp of transition row), 32 v2f ----
  v2f El[TAG / 2];
  {
    const float* row = trans + lane * TAG;
#pragma unroll
    for (int k = 0; k < TAG / 4; ++k) {
      v4f tv;
      __builtin_memcpy(&tv, row + 4 * k, sizeof(v4f));
      El[2 * k]     = v2f{__expf(tv.x), __expf(tv.y)};  // exp(-10000) -> 0, no NaN
      El[2 * k + 1] = v2f{__expf(tv.z), __expf(tv.w)};
    }
  }

  // per-lane invariant staging address: one gld_lds16 moves 4 rows (4 x 256 B)
  const float* gstage0 =
      feats + ((size_t)(lane >> 4) * BATCH + b) * TAG + ((lane & 15) << 2);

  auto stage_chunk = [&](int base_s, int nb) {
    const float* g0 = gstage0 + (size_t)base_s * (BATCH * TAG);
#pragma unroll
    for (int q = 0; q < 16; ++q) {
      gld_lds16(g0 + (size_t)(4 * q) * (BATCH * TAG), &fchunk[nb][q * 256]);
    }
  };

  float p = (lane == START_IDX) ? 1.0f : 0.0f;
  int etot = 0;  // running power-of-2 count: M = etot * ln2 (exact scaling)

  // ---- prologue: stage chunk 0 and wait for it ----
  stage_chunk(0, 0);
  asm volatile("s_waitcnt vmcnt(0)" ::: "memory");
  __builtin_amdgcn_sched_barrier(0);
  __builtin_amdgcn_wave_barrier();

  // One step. Chain: ds_write p -> 16 broadcast b128 reads -> 32 pk_fma -> tree -> mul.
  // RENORM's readlane/SALU work executes inside the DS round-trip gap (VALU idle).
  auto do_step = [&](float cgi, int par, bool renorm) {
    const unsigned pu = __float_as_uint(p);
    p_lds[par][lane] = p;
    __builtin_amdgcn_wave_barrier();  // pin reads below after the write

    float cgl = cgi;
    if (renorm) {
      const unsigned pb = __builtin_amdgcn_readlane(pu, 2);
      const unsigned eb = (pb == 0u) ? 127u : (pb >> 23);
      etot += (int)eb - 127;
      cgl = cgi * __uint_as_float((254u - eb) << 23);  // * 2^(127-eb), exact
    }

    const float* pl = &p_lds[par][0];
    v2f a0 = {0.f, 0.f}, a1 = {0.f, 0.f}, a2 = {0.f, 0.f}, a3 = {0.f, 0.f};
    v2f a4 = {0.f, 0.f}, a5 = {0.f, 0.f}, a6 = {0.f, 0.f}, a7 = {0.f, 0.f};
#pragma unroll
    for (int k = 0; k < 4; ++k) {
      v4f q0, q1, q2, q3;  // broadcast reads (all lanes same addr): conflict-free
      __builtin_memcpy(&q0, pl + 16 * k + 0,  sizeof(v4f));
      __builtin_memcpy(&q1, pl + 16 * k + 4,  sizeof(v4f));
      __builtin_memcpy(&q2, pl + 16 * k + 8,  sizeof(v4f));
      __builtin_memcpy(&q3, pl + 16 * k + 12, sizeof(v4f));
      a0 += v2f{q0.x, q0.y} * El[8 * k + 0];  // -> v_pk_fma_f32
      a1 += v2f{q0.z, q0.w} * El[8 * k + 1];
      a2 += v2f{q1.x, q1.y} * El[8 * k + 2];
      a3 += v2f{q1.z, q1.w} * El[8 * k + 3];
      a4 += v2f{q2.x, q2.y} * El[8 * k + 4];
      a5 += v2f{q2.z, q2.w} * El[8 * k + 5];
      a6 += v2f{q3.x, q3.y} * El[8 * k + 6];
      a7 += v2f{q3.z, q3.w} * El[8 * k + 7];
    }
    const v2f s0 = (a0 + a1) + (a2 + a3);
    const v2f s1 = (a4 + a5) + (a6 + a7);
    const v2f st = s0 + s1;
    const float t = st.x + st.y;
    p = t * cgl;  // single on-chain multiply
  };

  // 4-step group: exp(feat) batched off-chain; renorm only on step 0.
  auto group4 = [&](const float* fb, int s0) {
    float cg[4];
#pragma unroll
    for (int i = 0; i < 4; ++i) cg[i] = fb[(s0 + i) * TAG + lane];
#pragma unroll
    for (int i = 0; i < 4; ++i) cg[i] = __expf(cg[i]);
    do_step(cg[0], 0, true);   // s0 is a multiple of 4 -> parity 0
    do_step(cg[1], 1, false);
    do_step(cg[2], 0, false);
    do_step(cg[3], 1, false);
  };

  for (int c = 0;; ++c) {
    const int base = c * CHUNK;
    int n = L - base;
    if (n <= 0) break;
    if (n > CHUNK) n = CHUNK;

    const int nbase = base + CHUNK;
    if (nbase < S_LEN) stage_chunk(nbase, (c + 1) & 1);  // async, 64 steps ahead

    const float* fb = &fchunk[c & 1][0];

    if (n == CHUNK) {
      for (int g = 0; g < CHUNK / 4; ++g) group4(fb, 4 * g);
    } else {
      const int full = n >> 2;
      for (int g = 0; g < full; ++g) group4(fb, 4 * g);
      for (int i = full * 4; i < n; ++i) {  // tail (rare): per-step renorm is safe
        do_step(__expf(fb[i * TAG + lane]), i & 1, true);
      }
      break;  // L reached inside this chunk
    }

    if (nbase >= L) break;  // done; skip the drain

    // next chunk's loads were issued 64 steps ago: drain is ~free
    asm volatile("s_waitcnt vmcnt(0)" ::: "memory");
    __builtin_amdgcn_sched_barrier(0);
    __builtin_amdgcn_wave_barrier();
  }

  // drain any in-flight staging before LDS is deallocated at wave exit
  asm volatile("s_waitcnt vmcnt(0)" ::: "memory");

  // ---- epilogue: out[b] = logsumexp_j(etot*ln2 + log p_j + trans[END, j]) ----
  {
    const float a = (float)etot * LN2F + __logf(p) + trans[END_IDX * TAG + lane];
    float mx = a;  // p==0 -> a=-inf; lane 2 always finite so mx finite
#pragma unroll
    for (int off = 32; off >= 1; off >>= 1) mx = fmaxf(mx, __shfl_xor(mx, off, 64));
    float e = __expf(a - mx);
#pragma unroll
    for (int off = 32; off >= 1; off >>= 1) e += __shfl_xor(e, off, 64);
    if (lane == 0) out[b] = mx + __logf(e);
  }
}

extern "C" void kernel_launch(void* const* d_in, const int* in_sizes, int n_in,
                              void* d_out, int out_size, void* d_ws, size_t ws_size,
                              hipStream_t stream) {
  const float* feats = (const float*)d_in[0];
  const float* mask = (const float*)d_in[1];
  const float* trans = (const float*)d_in[2];
  float* out = (float*)d_out;
  crf_fwd_kernel<<<dim3(BATCH), dim3(64), 0, stream>>>(feats, mask, trans, out);
}